// Round 2
// baseline (687.314 us; speedup 1.0000x reference)
//
#include <hip/hip_runtime.h>
#include <math.h>

#define NTOK 16384
#define HDIM 4096
#define NEXP 64
#define SPLITS 4
#define KRANGE (HDIM / SPLITS)   // 1024 per block
#define KC 64                    // K chunk staged in LDS
#define TPW 8                    // tokens per wave
#define WAVES 8                  // waves per block
#define TOKTILE (TPW * WAVES)    // 64 tokens per block
#define WSTRIDE 68               // LDS row stride floats: 272 B (16B-aligned, bank 4e+k -> min-aliasing)

// lanes = experts; x is wave-uniform -> scalar pipe; W per-lane from LDS b128.
__global__ __launch_bounds__(512, 4) void gemm_smem(const float* __restrict__ x,
                                                    const float* __restrict__ W,
                                                    float* __restrict__ partial) {
  __shared__ __align__(16) float ws[NEXP][WSTRIDE];
  const int tile = blockIdx.x >> 2;   // token tile (0..255)
  const int split = blockIdx.x & 3;   // K split (0..3)
  const int kbase0 = split * KRANGE;
  const int lane = threadIdx.x & 63;  // expert id
  // wave-uniform token base, laundered to SGPR so x loads scalarize (s_load)
  const int wave = __builtin_amdgcn_readfirstlane((int)(threadIdx.x >> 6));
  const int tok0 = tile * TOKTILE + wave * TPW;
  const float* __restrict__ xrow = x + (size_t)tok0 * HDIM + kbase0;

  // W staging mapping: thread stages 8 floats of one expert row
  const int se = threadIdx.x >> 3;          // expert row 0..63
  const int sc = (threadIdx.x & 7) * 8;     // col group
  const float* wsrc = W + (size_t)se * HDIM + kbase0 + sc;

  float4 wa = *(const float4*)(wsrc);
  float4 wb = *(const float4*)(wsrc + 4);

  float p[TPW];
  double acc[TPW];
#pragma unroll
  for (int t = 0; t < TPW; ++t) { p[t] = 0.0f; acc[t] = 0.0; }

  for (int c = 0; c < KRANGE / KC; ++c) {
    // store staged W chunk
    *(float4*)&ws[se][sc] = wa;
    *(float4*)&ws[se][sc + 4] = wb;
    __syncthreads();
    // prefetch next chunk into registers
    if (c + 1 < KRANGE / KC) {
      wa = *(const float4*)(wsrc + (c + 1) * KC);
      wb = *(const float4*)(wsrc + (c + 1) * KC + 4);
    }
    const int kb = c * KC;  // offset within this split's K range
#pragma unroll
    for (int k = 0; k < KC; k += 4) {
      float4 wv = *(const float4*)&ws[lane][k];     // ds_read_b128, own expert row
      float4 xv[TPW];                               // wave-uniform -> s_load_dwordx4
#pragma unroll
      for (int t = 0; t < TPW; ++t)
        xv[t] = *(const float4*)(xrow + (size_t)t * HDIM + kb + k);
#pragma unroll
      for (int t = 0; t < TPW; ++t) {
        p[t] = fmaf(xv[t].x, wv.x, p[t]);
        p[t] = fmaf(xv[t].y, wv.y, p[t]);
        p[t] = fmaf(xv[t].z, wv.z, p[t]);
        p[t] = fmaf(xv[t].w, wv.w, p[t]);
      }
    }
#pragma unroll
    for (int t = 0; t < TPW; ++t) { acc[t] += (double)p[t]; p[t] = 0.0f; }
    __syncthreads();
  }

  // partial[split][token][expert], fp32 (summed in fixed fp64 order by topk)
#pragma unroll
  for (int t = 0; t < TPW; ++t)
    partial[((size_t)split * NTOK + tok0 + t) * NEXP + lane] = (float)acc[t];
}

// ---------------- split-reduce + top-8 + softmax + usage counts ----------------
// 1 wave per token; lane = expert. 16 tokens per 1024-thread block.
__global__ __launch_bounds__(1024) void topk_kernel(const float* __restrict__ partial,
                                                    float* __restrict__ out_scores,
                                                    float* __restrict__ out_idx,
                                                    unsigned int* __restrict__ counts) {
  __shared__ unsigned int lcnt[64];
  if (threadIdx.x < 64) lcnt[threadIdx.x] = 0u;
  __syncthreads();

  const int n = blockIdx.x * 16 + (threadIdx.x >> 6);
  const int e = threadIdx.x & 63;

  // deterministic fp64-ordered reduction over splits
  double s = 0.0;
#pragma unroll
  for (int sp = 0; sp < SPLITS; ++sp)
    s += (double)partial[((size_t)sp * NTOK + n) * NEXP + e];
  float live = (float)s;

  float vj[8];
  int ij[8];
#pragma unroll
  for (int j = 0; j < 8; ++j) {
    float bv = live;
    int bi = e;
#pragma unroll
    for (int off = 1; off < 64; off <<= 1) {
      float ov = __shfl_xor(bv, off);
      int oi = __shfl_xor(bi, off);
      if (ov > bv || (ov == bv && oi < bi)) { bv = ov; bi = oi; }
    }
    vj[j] = bv; ij[j] = bi;            // all lanes agree
    if (e == bi) live = -INFINITY;     // winner drops out
  }

  float m = vj[0], sum = 0.0f, sc[8];
#pragma unroll
  for (int j = 0; j < 8; ++j) { sc[j] = expf(vj[j] - m); sum += sc[j]; }
  float inv = 1.0f / sum;

  float myscore = 0.0f; int myidx = 0;
#pragma unroll
  for (int j = 0; j < 8; ++j)
    if (e == j) { myscore = sc[j] * inv; myidx = ij[j]; }
  if (e < 8) {
    out_scores[(size_t)n * 8 + e] = myscore;
    out_idx[(size_t)n * 8 + e] = (float)myidx;
    atomicAdd(&lcnt[myidx], 1u);
  }
  __syncthreads();
  if (threadIdx.x < 64) atomicAdd(&counts[threadIdx.x], lcnt[threadIdx.x]);
}

// ---------------- load-balance loss ----------------
__global__ __launch_bounds__(64) void loss_kernel(const unsigned int* __restrict__ counts,
                                                  float* __restrict__ out_loss) {
  const int e = threadIdx.x;
  double d = (double)counts[e] / (double)NTOK - 1.0 / 64.0;
  double sq = d * d;
#pragma unroll
  for (int off = 32; off > 0; off >>= 1) sq += __shfl_down(sq, off);
  if (e == 0) *out_loss = (float)(0.01 * sq);
}

extern "C" void kernel_launch(void* const* d_in, const int* in_sizes, int n_in,
                              void* d_out, int out_size, void* d_ws, size_t ws_size,
                              hipStream_t stream) {
  const float* x = (const float*)d_in[0];  // [16384][4096] fp32
  const float* W = (const float*)d_in[1];  // [64][4096] fp32 (expert-major, used directly)

  float* out = (float*)d_out;
  float* scores = out;                    // [16384][8]
  float* idxf = out + (size_t)NTOK * 8;   // [16384][8]
  float* loss = out + (size_t)NTOK * 16;  // scalar

  // ws: [0,256) counts; [256, 256+16MB) split partials fp32 [4][16384][64]
  unsigned int* counts = (unsigned int*)d_ws;
  float* partial = (float*)((char*)d_ws + 256);

  hipMemsetAsync(d_ws, 0, 256, stream);
  gemm_smem<<<256 * SPLITS, 512, 0, stream>>>(x, W, partial);
  topk_kernel<<<NTOK / 16, 1024, 0, stream>>>(partial, scores, idxf, counts);
  loss_kernel<<<1, 64, 0, stream>>>(counts, loss);
}

// Round 3
// 455.928 us; speedup vs baseline: 1.5075x; 1.5075x over previous
//
#include <hip/hip_runtime.h>
#include <math.h>

#define NTOK 16384
#define HDIM 4096
#define NEXP 64
#define SPLITS 4
#define KRANGE (HDIM / SPLITS)  // 1024 K per block
#define KC 32                   // K chunk staged in LDS
#define TOKTILE 128             // tokens per block
#define XSTRIDE (TOKTILE + 4)   // 132: k-major x tile row stride (floats)
#define WSTRIDE (NEXP + 4)      // 68:  k-major w tile row stride (floats)

// Register-tiled fp32 GEMM. Block: 128 tok x 64 exp x K=1024 (split-K).
// LDS tiles are k-major so per-k fragment reads are contiguous float4:
//   x-frag: 4 distinct addrs/wave (16-way broadcast), conflict-free
//   w-frag: 16 addrs, 2 per 4-bank window -> 2-way (free per m136)
// Per k per thread: 2 ds_read_b128 + 16 v_fma (LDS ~0.1x of VALU demand).
__global__ __launch_bounds__(512, 4) void gemm_tile(const float* __restrict__ x,
                                                    const float* __restrict__ W,
                                                    float* __restrict__ partial) {
  __shared__ __align__(16) float xs[KC][XSTRIDE];
  __shared__ __align__(16) float ws[KC][WSTRIDE];
  const int tile = (int)blockIdx.x >> 2;
  const int split = (int)blockIdx.x & 3;
  const int kbase = split * KRANGE;
  const int tok0 = tile * TOKTILE;
  const int t = (int)threadIdx.x;
  const int eg = t & 15;  // experts 4*eg .. 4*eg+3
  const int tg = t >> 4;  // tokens 4*tg .. 4*tg+3 (0..31)

  // staging: thread loads 2 float4 of x (rows srow, srow+64) and 1 float4 of W
  const int srow = t >> 3;        // 0..63
  const int sc4 = (t & 7) * 4;    // 0,4,...,28
  const float* xsrc0 = x + (size_t)(tok0 + srow) * HDIM + kbase + sc4;
  const float* xsrc1 = x + (size_t)(tok0 + 64 + srow) * HDIM + kbase + sc4;
  const float* wsrc = W + (size_t)srow * HDIM + kbase + sc4;

  float4 xa0 = *(const float4*)xsrc0;
  float4 xa1 = *(const float4*)xsrc1;
  float4 wa = *(const float4*)wsrc;

  double acc[4][4];
#pragma unroll
  for (int i = 0; i < 4; ++i)
#pragma unroll
    for (int j = 0; j < 4; ++j) acc[i][j] = 0.0;

  for (int c = 0; c < KRANGE / KC; ++c) {
    // transposed scatter into k-major LDS tiles (b32 writes, ~2% of compute)
#pragma unroll
    for (int j = 0; j < 4; ++j) {
      xs[sc4 + j][srow] = ((const float*)&xa0)[j];
      xs[sc4 + j][64 + srow] = ((const float*)&xa1)[j];
      ws[sc4 + j][srow] = ((const float*)&wa)[j];
    }
    __syncthreads();
    if (c + 1 < KRANGE / KC) {  // register prefetch of next chunk
      xa0 = *(const float4*)(xsrc0 + (c + 1) * KC);
      xa1 = *(const float4*)(xsrc1 + (c + 1) * KC);
      wa = *(const float4*)(wsrc + (c + 1) * KC);
    }
    float p[4][4];
#pragma unroll
    for (int i = 0; i < 4; ++i)
#pragma unroll
      for (int j = 0; j < 4; ++j) p[i][j] = 0.0f;

#pragma unroll 8
    for (int k = 0; k < KC; ++k) {
      float4 xv = *(const float4*)&xs[k][4 * tg];  // ds_read_b128, broadcast
      float4 wv = *(const float4*)&ws[k][4 * eg];  // ds_read_b128, 2-way free
#pragma unroll
      for (int i = 0; i < 4; ++i) {
        float xi = ((const float*)&xv)[i];
        p[i][0] = fmaf(xi, wv.x, p[i][0]);
        p[i][1] = fmaf(xi, wv.y, p[i][1]);
        p[i][2] = fmaf(xi, wv.z, p[i][2]);
        p[i][3] = fmaf(xi, wv.w, p[i][3]);
      }
    }
#pragma unroll
    for (int i = 0; i < 4; ++i)
#pragma unroll
      for (int j = 0; j < 4; ++j) acc[i][j] += (double)p[i][j];
    __syncthreads();
  }

  // partial[split][expert][token] so topk's thread-per-token reads coalesce
#pragma unroll
  for (int j = 0; j < 4; ++j) {
    float4 o;
    o.x = (float)acc[0][j]; o.y = (float)acc[1][j];
    o.z = (float)acc[2][j]; o.w = (float)acc[3][j];
    *(float4*)&partial[((size_t)split * NEXP + 4 * eg + j) * NTOK + tok0 + 4 * tg] = o;
  }
}

// ---------------- split-reduce + top-8 + softmax + usage counts ----------------
// Thread per token (R1-verified insertion); partial reads coalesced across lanes.
__global__ __launch_bounds__(128) void topk_kernel(const float* __restrict__ partial,
                                                   float* __restrict__ out_scores,
                                                   float* __restrict__ out_idx,
                                                   unsigned int* __restrict__ counts) {
  const int n = blockIdx.x * 128 + threadIdx.x;
  __shared__ unsigned int lcnt[64];
  if (threadIdx.x < 64) lcnt[threadIdx.x] = 0u;
  __syncthreads();

  float v[8];
  int id[8];
#pragma unroll
  for (int j = 0; j < 8; ++j) { v[j] = -INFINITY; id[j] = 0; }

  for (int e = 0; e < 64; ++e) {
    double s = 0.0;
#pragma unroll
    for (int sp = 0; sp < SPLITS; ++sp)
      s += (double)partial[((size_t)sp * NEXP + e) * NTOK + n];
    float val = (float)s;
    // stable descending insert: strict '>' keeps earlier (lower) index on ties
#pragma unroll
    for (int j = 7; j >= 0; --j) {
      if (val > v[j]) {
        if (j == 0 || val <= v[j - 1]) { v[j] = val; id[j] = e; }
        else { v[j] = v[j - 1]; id[j] = id[j - 1]; }
      }
    }
  }

  float ex[8], s = 0.0f;
#pragma unroll
  for (int j = 0; j < 8; ++j) { ex[j] = expf(v[j] - v[0]); s += ex[j]; }
  float inv = 1.0f / s;

#pragma unroll
  for (int j = 0; j < 8; ++j) {
    out_scores[(size_t)n * 8 + j] = ex[j] * inv;
    out_idx[(size_t)n * 8 + j] = (float)id[j];
    atomicAdd(&lcnt[id[j]], 1u);
  }
  __syncthreads();
  if (threadIdx.x < 64) atomicAdd(&counts[threadIdx.x], lcnt[threadIdx.x]);
}

// ---------------- load-balance loss ----------------
__global__ __launch_bounds__(64) void loss_kernel(const unsigned int* __restrict__ counts,
                                                  float* __restrict__ out_loss) {
  const int e = threadIdx.x;
  double d = (double)counts[e] / (double)NTOK - 1.0 / 64.0;
  double sq = d * d;
#pragma unroll
  for (int off = 32; off > 0; off >>= 1) sq += __shfl_down(sq, off);
  if (e == 0) *out_loss = (float)(0.01 * sq);
}

extern "C" void kernel_launch(void* const* d_in, const int* in_sizes, int n_in,
                              void* d_out, int out_size, void* d_ws, size_t ws_size,
                              hipStream_t stream) {
  const float* x = (const float*)d_in[0];  // [16384][4096] fp32
  const float* W = (const float*)d_in[1];  // [64][4096] fp32

  float* out = (float*)d_out;
  float* scores = out;                    // [16384][8]
  float* idxf = out + (size_t)NTOK * 8;   // [16384][8]
  float* loss = out + (size_t)NTOK * 16;  // scalar

  // ws: [0,256) counts; [256, 256+16MB) split partials fp32 [4][64][16384]
  unsigned int* counts = (unsigned int*)d_ws;
  float* partial = (float*)((char*)d_ws + 256);

  hipMemsetAsync(d_ws, 0, 256, stream);
  gemm_tile<<<(NTOK / TOKTILE) * SPLITS, 512, 0, stream>>>(x, W, partial);
  topk_kernel<<<NTOK / 128, 128, 0, stream>>>(partial, scores, idxf, counts);
  loss_kernel<<<1, 64, 0, stream>>>(counts, loss);
}